// Round 1
// baseline (49.944 us; speedup 1.0000x reference)
//
#include <hip/hip_runtime.h>

// out[b,s,d] = relu(x[b,s] * W[s,d] + bias[s,d])
// B=256, S=512, D=512 (all fp32). Memory-bound: 268 MB output write dominates.

constexpr int B = 256;
constexpr int S = 512;
constexpr int D = 512;
constexpr int D4 = D / 4;              // 128 float4 per row
constexpr int TOTAL4 = B * S * D4;     // 16,777,216 float4 elements

__global__ void __launch_bounds__(256) od2d_kernel(
    const float* __restrict__ x,      // [B*S]
    const float4* __restrict__ W4,    // [S*D4]
    const float4* __restrict__ b4,    // [S*D4]
    float4* __restrict__ o4)          // [B*S*D4]
{
    const unsigned stride = gridDim.x * blockDim.x;
    for (unsigned i = blockIdx.x * blockDim.x + threadIdx.x; i < TOTAL4; i += stride) {
        const unsigned d4 = i & (D4 - 1);        // i % 128
        const unsigned bs = i >> 7;              // i / 128
        const unsigned s  = bs & (S - 1);        // bs % 512
        const float xv = x[bs];
        const unsigned wi = (s << 7) + d4;       // s*128 + d4
        const float4 w  = W4[wi];
        const float4 bb = b4[wi];
        float4 r;
        r.x = fmaxf(fmaf(xv, w.x, bb.x), 0.0f);
        r.y = fmaxf(fmaf(xv, w.y, bb.y), 0.0f);
        r.z = fmaxf(fmaf(xv, w.z, bb.z), 0.0f);
        r.w = fmaxf(fmaf(xv, w.w, bb.w), 0.0f);
        o4[i] = r;
    }
}

extern "C" void kernel_launch(void* const* d_in, const int* in_sizes, int n_in,
                              void* d_out, int out_size, void* d_ws, size_t ws_size,
                              hipStream_t stream) {
    const float*  x  = (const float*)d_in[0];
    const float4* W4 = (const float4*)d_in[1];
    const float4* b4 = (const float4*)d_in[2];
    float4* o4 = (float4*)d_out;

    const int block = 256;
    const int grid  = 2048;   // grid-stride, 32 iters/thread
    od2d_kernel<<<grid, block, 0, stream>>>(x, W4, b4, o4);
}